// Round 2
// baseline (777.344 us; speedup 1.0000x reference)
//
#include <hip/hip_runtime.h>
#include <math.h>

#define NN 50000
#define NE 800000
#define NEG 0.2f
#define CHUNK 32

// ---------------- GEMM: out[N,256] = feat[N,128] @ W[128,256] + b ----------------
__global__ __launch_bounds__(256) void gemm_proj(
    const float* __restrict__ feat, const float* __restrict__ W,
    const float* __restrict__ b, float* __restrict__ out, int n_rows)
{
    __shared__ float lds[64 * 128];
    const int row0 = blockIdx.x * 64;
    const int tid = threadIdx.x;
    for (int i = tid; i < 64 * 128; i += 256) {
        int r = row0 + (i >> 7);
        lds[i] = (r < n_rows) ? feat[row0 * 128 + i] : 0.0f;
    }
    __syncthreads();
    const int col = tid;  // 0..255
    float acc[64];
#pragma unroll
    for (int r = 0; r < 64; ++r) acc[r] = 0.0f;
    for (int k = 0; k < 128; k += 4) {
        float w0 = W[(k + 0) * 256 + col];
        float w1 = W[(k + 1) * 256 + col];
        float w2 = W[(k + 2) * 256 + col];
        float w3 = W[(k + 3) * 256 + col];
#pragma unroll
        for (int r = 0; r < 64; ++r) {
            const float4 f = *reinterpret_cast<const float4*>(&lds[(r << 7) + k]);
            acc[r] = fmaf(f.x, w0, acc[r]);
            acc[r] = fmaf(f.y, w1, acc[r]);
            acc[r] = fmaf(f.z, w2, acc[r]);
            acc[r] = fmaf(f.w, w3, acc[r]);
        }
    }
    const float bias = b[col];
#pragma unroll
    for (int r = 0; r < 64; ++r) {
        int row = row0 + r;
        if (row < n_rows) out[row * 256 + col] = acc[r] + bias;
    }
}

// ---------------- CSR build ----------------
__global__ void count_deg(const int* __restrict__ dst, int* __restrict__ deg)
{
    int e = blockIdx.x * blockDim.x + threadIdx.x;
    if (e < NE) atomicAdd(&deg[dst[e]], 1);
}

__global__ __launch_bounds__(1024) void scan_deg(const int* __restrict__ deg,
                                                 int* __restrict__ row_start)
{
    __shared__ int part[1024];
    const int tid = threadIdx.x;
    const int CH = (NN + 1023) / 1024;  // 49
    int begin = tid * CH;
    int end_ = begin + CH; if (end_ > NN) end_ = NN;
    int s = 0;
    for (int i = begin; i < end_; ++i) s += deg[i];
    part[tid] = s;
    __syncthreads();
    for (int off = 1; off < 1024; off <<= 1) {
        int v = (tid >= off) ? part[tid - off] : 0;
        __syncthreads();
        part[tid] += v;
        __syncthreads();
    }
    int base = (tid > 0) ? part[tid - 1] : 0;
    for (int i = begin; i < end_; ++i) {
        row_start[i] = base;
        base += deg[i];
    }
    if (tid == 1023) row_start[NN] = part[1023];
}

// write src node id into CSR-position order (no edge_list indirection later)
__global__ void scatter_src(const int* __restrict__ src, const int* __restrict__ dst,
                            const int* __restrict__ row_start,
                            int* __restrict__ cursor, int* __restrict__ src_sorted)
{
    int e = blockIdx.x * blockDim.x + threadIdx.x;
    if (e < NE) {
        int d = dst[e];
        int pos = row_start[d] + atomicAdd(&cursor[d], 1);
        src_sorted[pos] = src[e];
    }
}

// ---------------- Layer-1 fused: block = node, wave = head, chunked two-pass ----
__global__ __launch_bounds__(256) void gat1_fused(
    const float* __restrict__ hs, const float* __restrict__ hd,
    const float* __restrict__ attn, const int* __restrict__ src_sorted,
    const int* __restrict__ row_start, float* __restrict__ h1out)
{
    __shared__ float sc_lds[4][CHUNK];
    const int n = blockIdx.x;
    const int h = threadIdx.x >> 6;
    const int lane = threadIdx.x & 63;
    const int fi = threadIdx.x;  // h*64 + lane
    const float hdv = hd[(size_t)n * 256 + fi];
    const float av = attn[fi];
    const int beg = row_start[n], end_ = row_start[n + 1];

    float m = -INFINITY, den = 0.0f, acc = 0.0f;

    for (int cb = beg; cb < end_; cb += CHUNK) {
        const int ce = (cb + CHUNK < end_) ? cb + CHUNK : end_;
        float cm = -INFINITY;
        // pass 1: per-edge attention scores (stored per-head in LDS)
        for (int i = cb; i < ce; ++i) {
            const int s = src_sorted[i];
            float x = hs[(size_t)s * 256 + fi];
            float t = x + hdv;
            t = (t > 0.0f) ? t : NEG * t;
            float p = t * av;
#pragma unroll
            for (int off = 32; off; off >>= 1) p += __shfl_xor(p, off);
            if (lane == 0) sc_lds[h][i - cb] = p;
            cm = fmaxf(cm, p);
        }
        const float mn = fmaxf(m, cm);
        const float rescale = __expf(m - mn);  // m=-inf first chunk -> 0; den/acc are 0
        den *= rescale;
        acc *= rescale;
        m = mn;
        // pass 2: weighted aggregation; x re-gather hits L1 (<=32KB window)
        for (int i = cb; i < ce; ++i) {
            const int s = src_sorted[i];
            float x = hs[(size_t)s * 256 + fi];
            float w = __expf(sc_lds[h][i - cb] - m);
            den += w;
            acc = fmaf(w, x, acc);
        }
    }
    float o = (den > 0.0f) ? acc / den : 0.0f;
    o = (o > 0.0f) ? o : __expf(o) - 1.0f;  // ELU fused
    h1out[(size_t)n * 256 + fi] = o;
}

// ---------------- Layer-2 projections: wave per node ----------------
__global__ __launch_bounds__(256) void gemv2(
    const float* __restrict__ h1,
    const float* __restrict__ W2s, const float* __restrict__ b2s,
    const float* __restrict__ W2d, const float* __restrict__ b2d,
    float* __restrict__ hs2, float* __restrict__ hd2)
{
    const int n = blockIdx.x * 4 + (threadIdx.x >> 6);
    const int lane = threadIdx.x & 63;
    if (n >= NN) return;
    const float4 x = *reinterpret_cast<const float4*>(&h1[(size_t)n * 256 + lane * 4]);
    float xv[4] = {x.x, x.y, x.z, x.w};
    float s0 = 0, s1 = 0, d0 = 0, d1 = 0;
#pragma unroll
    for (int j = 0; j < 4; ++j) {
        int k = lane * 4 + j;
        s0 = fmaf(xv[j], W2s[k * 2 + 0], s0);
        s1 = fmaf(xv[j], W2s[k * 2 + 1], s1);
        d0 = fmaf(xv[j], W2d[k * 2 + 0], d0);
        d1 = fmaf(xv[j], W2d[k * 2 + 1], d1);
    }
#pragma unroll
    for (int off = 32; off; off >>= 1) {
        s0 += __shfl_xor(s0, off);
        s1 += __shfl_xor(s1, off);
        d0 += __shfl_xor(d0, off);
        d1 += __shfl_xor(d1, off);
    }
    if (lane == 0) {
        hs2[n * 2 + 0] = s0 + b2s[0];
        hs2[n * 2 + 1] = s1 + b2s[1];
        hd2[n * 2 + 0] = d0 + b2d[0];
        hd2[n * 2 + 1] = d1 + b2d[1];
    }
}

// ---------------- Layer-2: wave per node, lane per edge ----------------
__global__ __launch_bounds__(256) void node2_kernel(
    const float* __restrict__ hs2, const float* __restrict__ hd2,
    const float* __restrict__ attn2, const int* __restrict__ src_sorted,
    const int* __restrict__ row_start, float* __restrict__ out)
{
    const int n = blockIdx.x * 4 + (threadIdx.x >> 6);
    const int lane = threadIdx.x & 63;
    if (n >= NN) return;
    const float a0 = attn2[0], a1 = attn2[1];
    const float h0 = hd2[n * 2 + 0], h1v = hd2[n * 2 + 1];
    const int beg = row_start[n], end_ = row_start[n + 1];
    float m = -INFINITY, den = 0.0f, A0 = 0.0f, A1 = 0.0f;
    for (int i = beg + lane; i < end_; i += 64) {
        const int s = src_sorted[i];
        float x0 = hs2[s * 2 + 0], x1 = hs2[s * 2 + 1];
        float t0 = x0 + h0;  t0 = (t0 > 0.0f) ? t0 : NEG * t0;
        float t1 = x1 + h1v; t1 = (t1 > 0.0f) ? t1 : NEG * t1;
        float p = fmaf(t0, a0, t1 * a1);
        float mn = fmaxf(m, p);
        float c = __expf(m - mn);  // first iter: exp(-inf)=0; p finite so no NaN
        float w = __expf(p - mn);
        den = den * c + w;
        A0 = A0 * c + w * x0;
        A1 = A1 * c + w * x1;
        m = mn;
    }
    // butterfly merge of (m, den, A0, A1) across 64 lanes
#pragma unroll
    for (int off = 1; off < 64; off <<= 1) {
        float m2 = __shfl_xor(m, off);
        float d2 = __shfl_xor(den, off);
        float b0 = __shfl_xor(A0, off);
        float b1 = __shfl_xor(A1, off);
        float mn = fmaxf(m, m2);
        float c1 = (m < mn) ? __expf(m - mn) : 1.0f;    // guards -inf/-inf -> NaN
        float c2 = (m2 < mn) ? __expf(m2 - mn) : 1.0f;
        den = den * c1 + d2 * c2;
        A0 = A0 * c1 + b0 * c2;
        A1 = A1 * c1 + b1 * c2;
        m = mn;
    }
    if (lane == 0) {
        out[n * 2 + 0] = (den > 0.0f) ? A0 / den : 0.0f;
        out[n * 2 + 1] = (den > 0.0f) ? A1 / den : 0.0f;
    }
}

// ---------------- launch ----------------
extern "C" void kernel_launch(void* const* d_in, const int* in_sizes, int n_in,
                              void* d_out, int out_size, void* d_ws, size_t ws_size,
                              hipStream_t stream)
{
    const float* feat  = (const float*)d_in[0];
    const int*   src   = (const int*)d_in[1];
    const int*   dst   = (const int*)d_in[2];
    const float* W1s   = (const float*)d_in[3];
    const float* b1s   = (const float*)d_in[4];
    const float* W1d   = (const float*)d_in[5];
    const float* b1d   = (const float*)d_in[6];
    const float* attn1 = (const float*)d_in[7];
    const float* W2s   = (const float*)d_in[8];
    const float* b2s   = (const float*)d_in[9];
    const float* W2d   = (const float*)d_in[10];
    const float* b2d   = (const float*)d_in[11];
    const float* attn2 = (const float*)d_in[12];
    float* out = (float*)d_out;

    char* ws = (char*)d_ws;
    size_t off = 0;
    auto alloc = [&](size_t bytes) {
        char* p = ws + off;
        off += (bytes + 255) & ~size_t(255);
        return p;
    };
    float* hs1        = (float*)alloc((size_t)NN * 256 * 4);
    float* hd1        = (float*)alloc((size_t)NN * 256 * 4);
    float* h1         = (float*)alloc((size_t)NN * 256 * 4);
    int*   src_sorted = (int*)alloc((size_t)NE * 4);
    int*   row_start  = (int*)alloc((size_t)(NN + 1) * 4);
    int*   deg        = (int*)alloc((size_t)NN * 4);
    int*   cursor     = (int*)alloc((size_t)NN * 4);
    float* hs2        = (float*)alloc((size_t)NN * 2 * 4);
    float* hd2        = (float*)alloc((size_t)NN * 2 * 4);
    (void)ws_size; (void)n_in; (void)in_sizes; (void)out_size;

    hipMemsetAsync(deg, 0, (size_t)NN * 4, stream);
    hipMemsetAsync(cursor, 0, (size_t)NN * 4, stream);

    const int gemm_blocks = (NN + 63) / 64;  // 782
    gemm_proj<<<gemm_blocks, 256, 0, stream>>>(feat, W1s, b1s, hs1, NN);
    gemm_proj<<<gemm_blocks, 256, 0, stream>>>(feat, W1d, b1d, hd1, NN);

    const int eb = (NE + 255) / 256;  // 3125
    count_deg<<<eb, 256, 0, stream>>>(dst, deg);
    scan_deg<<<1, 1024, 0, stream>>>(deg, row_start);
    scatter_src<<<eb, 256, 0, stream>>>(src, dst, row_start, cursor, src_sorted);

    gat1_fused<<<NN, 256, 0, stream>>>(hs1, hd1, attn1, src_sorted, row_start, h1);

    gemv2<<<(NN + 3) / 4, 256, 0, stream>>>(h1, W2s, b2s, W2d, b2d, hs2, hd2);

    node2_kernel<<<(NN + 3) / 4, 256, 0, stream>>>(hs2, hd2, attn2, src_sorted,
                                                   row_start, out);
}

// Round 3
// 712.141 us; speedup vs baseline: 1.0916x; 1.0916x over previous
//
#include <hip/hip_runtime.h>
#include <math.h>

#define NN 50000
#define NE 800000
#define NEG 0.2f

// ---------- fused dual GEMM: out[N,256] = feat[N,128] @ W + b  (gridDim.y picks W1s/W1d)
__global__ __launch_bounds__(256) void gemm_proj(
    const float* __restrict__ feat,
    const float* __restrict__ Wa, const float* __restrict__ ba, float* __restrict__ outa,
    const float* __restrict__ Wb, const float* __restrict__ bb, float* __restrict__ outb,
    int n_rows)
{
    const float* W = blockIdx.y ? Wb : Wa;
    const float* bv = blockIdx.y ? bb : ba;
    float* out = blockIdx.y ? outb : outa;

    __shared__ float fT[64][128];   // 32 KB feat tile, row-major
    __shared__ float wT[16][256];   // 16 KB W k-chunk

    const int row0 = blockIdx.x * 64;
    const int tid = threadIdx.x;

    // stage feat tile (coalesced float4, conflict-free b128 writes)
    {
        const float4* f4 = reinterpret_cast<const float4*>(feat);
#pragma unroll
        for (int p = 0; p < 8; ++p) {
            int idx = p * 256 + tid;
            int r = idx >> 5, c4 = idx & 31;
            int gr = row0 + r;
            float4 v = (gr < n_rows) ? f4[(size_t)gr * 32 + c4]
                                     : make_float4(0.f, 0.f, 0.f, 0.f);
            *reinterpret_cast<float4*>(&fT[r][c4 * 4]) = v;
        }
    }

    const int tm = tid >> 5;   // 0..7  -> rows tm + ri*8
    const int tn = tid & 31;   // 0..31 -> cols tn + ci*32
    float acc[8][8];
#pragma unroll
    for (int ri = 0; ri < 8; ++ri)
#pragma unroll
        for (int ci = 0; ci < 8; ++ci) acc[ri][ci] = 0.0f;

    const float4* W4 = reinterpret_cast<const float4*>(W);
    for (int k0 = 0; k0 < 128; k0 += 16) {
        __syncthreads();
#pragma unroll
        for (int p = 0; p < 4; ++p) {
            int idx = p * 256 + tid;
            int r = idx >> 6, c4 = idx & 63;
            *reinterpret_cast<float4*>(&wT[r][c4 * 4]) = W4[(size_t)(k0 + r) * 64 + c4];
        }
        __syncthreads();
#pragma unroll
        for (int kk = 0; kk < 16; ++kk) {
            float a[8], w[8];
#pragma unroll
            for (int ri = 0; ri < 8; ++ri) a[ri] = fT[tm + ri * 8][k0 + kk];
#pragma unroll
            for (int ci = 0; ci < 8; ++ci) w[ci] = wT[kk][tn + ci * 32];
#pragma unroll
            for (int ri = 0; ri < 8; ++ri)
#pragma unroll
                for (int ci = 0; ci < 8; ++ci)
                    acc[ri][ci] = fmaf(a[ri], w[ci], acc[ri][ci]);
        }
    }
#pragma unroll
    for (int ri = 0; ri < 8; ++ri) {
        int row = row0 + tm + ri * 8;
        if (row < n_rows) {
#pragma unroll
            for (int ci = 0; ci < 8; ++ci) {
                int col = tn + ci * 32;
                out[(size_t)row * 256 + col] = acc[ri][ci] + bv[col];
            }
        }
    }
}

// ---------------- CSR build ----------------
__global__ void count_deg(const int* __restrict__ dst, int* __restrict__ deg)
{
    int e = blockIdx.x * blockDim.x + threadIdx.x;
    if (e < NE) atomicAdd(&deg[dst[e]], 1);
}

__global__ __launch_bounds__(1024) void scan_deg(const int* __restrict__ deg,
                                                 int* __restrict__ row_start)
{
    __shared__ int part[1024];
    const int tid = threadIdx.x;
    const int CH = (NN + 1023) / 1024;  // 49
    int begin = tid * CH;
    int end_ = begin + CH; if (end_ > NN) end_ = NN;
    int s = 0;
    for (int i = begin; i < end_; ++i) s += deg[i];
    part[tid] = s;
    __syncthreads();
    for (int off = 1; off < 1024; off <<= 1) {
        int v = (tid >= off) ? part[tid - off] : 0;
        __syncthreads();
        part[tid] += v;
        __syncthreads();
    }
    int base = (tid > 0) ? part[tid - 1] : 0;
    for (int i = begin; i < end_; ++i) {
        row_start[i] = base;
        base += deg[i];
    }
    if (tid == 1023) row_start[NN] = part[1023];
}

__global__ void scatter_src(const int* __restrict__ src, const int* __restrict__ dst,
                            const int* __restrict__ row_start,
                            int* __restrict__ cursor, int* __restrict__ src_sorted)
{
    int e = blockIdx.x * blockDim.x + threadIdx.x;
    if (e < NE) {
        int d = dst[e];
        int pos = row_start[d] + atomicAdd(&cursor[d], 1);
        src_sorted[pos] = src[e];
    }
}

// ---- Layer-1 fused (defer-max single pass) + fused layer-2 projection epilogue ----
__global__ __launch_bounds__(256) void gat1_fused(
    const float* __restrict__ hs, const float* __restrict__ hd,
    const float* __restrict__ attn, const int* __restrict__ src_sorted,
    const int* __restrict__ row_start,
    const float* __restrict__ W2s, const float* __restrict__ b2s,
    const float* __restrict__ W2d, const float* __restrict__ b2d,
    float* __restrict__ hs2, float* __restrict__ hd2)
{
    const int n = blockIdx.x;
    const int h = threadIdx.x >> 6;
    const int lane = threadIdx.x & 63;
    const int fi = threadIdx.x;  // h*64 + lane
    const float hdv = hd[(size_t)n * 256 + fi];
    const float av = attn[fi];
    const int beg = row_start[n], end_ = row_start[n + 1];

    float m = -INFINITY, den = 0.0f, acc = 0.0f;

    for (int cb = beg; cb < end_; cb += 16) {
        // coalesced edge-id fetch; lanes 0..15 meaningful, broadcast below
        int idx = cb + (lane & 15);
        int se = src_sorted[(idx < end_) ? idx : end_ - 1];
#pragma unroll
        for (int j = 0; j < 16; ++j) {
            const int s = __shfl(se, j);              // readlane -> SGPR gather base
            float x = hs[(size_t)s * 256 + fi];       // 256B coalesced gather
            float t = x + hdv;
            t = fmaxf(t, NEG * t);                    // leaky_relu (NEG>0)
            float p = t * av;
#pragma unroll
            for (int off = 32; off; off >>= 1) p += __shfl_xor(p, off);
            p = (cb + j < end_) ? p : -INFINITY;      // mask tail (dup-load harmless)
            if (p > m + 8.0f) {                       // rare, wave-uniform rescale
                float rs = __expf(m - p);             // m=-inf first time -> 0
                den *= rs; acc *= rs; m = p;
            }
            float w = __expf(p - m);                  // <= e^8, exact after final /den
            den += w;
            acc = fmaf(w, x, acc);
        }
    }

    float o = (den > 0.0f) ? acc / den : 0.0f;
    o = (o > 0.0f) ? o : __expf(o) - 1.0f;            // ELU fused

    // fused layer-2 projection: hs2/hd2[n] = h1[n] @ W2{s,d} + b2{s,d}
    float s0 = o * W2s[fi * 2 + 0], s1 = o * W2s[fi * 2 + 1];
    float d0 = o * W2d[fi * 2 + 0], d1 = o * W2d[fi * 2 + 1];
#pragma unroll
    for (int off = 32; off; off >>= 1) {
        s0 += __shfl_xor(s0, off);
        s1 += __shfl_xor(s1, off);
        d0 += __shfl_xor(d0, off);
        d1 += __shfl_xor(d1, off);
    }
    __shared__ float red[4][4];
    if (lane == 0) {
        red[h][0] = s0; red[h][1] = s1; red[h][2] = d0; red[h][3] = d1;
    }
    __syncthreads();
    if (threadIdx.x < 2) {
        int c = threadIdx.x;
        hs2[(size_t)n * 2 + c] =
            red[0][c] + red[1][c] + red[2][c] + red[3][c] + b2s[c];
    } else if (threadIdx.x >= 64 && threadIdx.x < 66) {
        int c = threadIdx.x - 64;
        hd2[(size_t)n * 2 + c] =
            red[0][2 + c] + red[1][2 + c] + red[2][2 + c] + red[3][2 + c] + b2d[c];
    }
}

// ---------------- Layer-2: wave per node, lane per edge ----------------
__global__ __launch_bounds__(256) void node2_kernel(
    const float* __restrict__ hs2, const float* __restrict__ hd2,
    const float* __restrict__ attn2, const int* __restrict__ src_sorted,
    const int* __restrict__ row_start, float* __restrict__ out)
{
    const int n = blockIdx.x * 4 + (threadIdx.x >> 6);
    const int lane = threadIdx.x & 63;
    if (n >= NN) return;
    const float a0 = attn2[0], a1 = attn2[1];
    const float h0 = hd2[n * 2 + 0], h1v = hd2[n * 2 + 1];
    const int beg = row_start[n], end_ = row_start[n + 1];
    float m = -INFINITY, den = 0.0f, A0 = 0.0f, A1 = 0.0f;
    for (int i = beg + lane; i < end_; i += 64) {
        const int s = src_sorted[i];
        float x0 = hs2[s * 2 + 0], x1 = hs2[s * 2 + 1];
        float t0 = x0 + h0;  t0 = fmaxf(t0, NEG * t0);
        float t1 = x1 + h1v; t1 = fmaxf(t1, NEG * t1);
        float p = fmaf(t0, a0, t1 * a1);
        float mn = fmaxf(m, p);
        float c = __expf(m - mn);
        float w = __expf(p - mn);
        den = den * c + w;
        A0 = A0 * c + w * x0;
        A1 = A1 * c + w * x1;
        m = mn;
    }
#pragma unroll
    for (int off = 1; off < 64; off <<= 1) {
        float m2 = __shfl_xor(m, off);
        float d2 = __shfl_xor(den, off);
        float b0 = __shfl_xor(A0, off);
        float b1 = __shfl_xor(A1, off);
        float mn = fmaxf(m, m2);
        float c1 = (m < mn) ? __expf(m - mn) : 1.0f;
        float c2 = (m2 < mn) ? __expf(m2 - mn) : 1.0f;
        den = den * c1 + d2 * c2;
        A0 = A0 * c1 + b0 * c2;
        A1 = A1 * c1 + b1 * c2;
        m = mn;
    }
    if (lane == 0) {
        out[n * 2 + 0] = (den > 0.0f) ? A0 / den : 0.0f;
        out[n * 2 + 1] = (den > 0.0f) ? A1 / den : 0.0f;
    }
}

// ---------------- launch ----------------
extern "C" void kernel_launch(void* const* d_in, const int* in_sizes, int n_in,
                              void* d_out, int out_size, void* d_ws, size_t ws_size,
                              hipStream_t stream)
{
    const float* feat  = (const float*)d_in[0];
    const int*   src   = (const int*)d_in[1];
    const int*   dst   = (const int*)d_in[2];
    const float* W1s   = (const float*)d_in[3];
    const float* b1s   = (const float*)d_in[4];
    const float* W1d   = (const float*)d_in[5];
    const float* b1d   = (const float*)d_in[6];
    const float* attn1 = (const float*)d_in[7];
    const float* W2s   = (const float*)d_in[8];
    const float* b2s   = (const float*)d_in[9];
    const float* W2d   = (const float*)d_in[10];
    const float* b2d   = (const float*)d_in[11];
    const float* attn2 = (const float*)d_in[12];
    float* out = (float*)d_out;

    char* ws = (char*)d_ws;
    size_t off = 0;
    auto alloc = [&](size_t bytes) {
        char* p = ws + off;
        off += (bytes + 255) & ~size_t(255);
        return p;
    };
    float* hs1        = (float*)alloc((size_t)NN * 256 * 4);
    float* hd1        = (float*)alloc((size_t)NN * 256 * 4);
    int*   src_sorted = (int*)alloc((size_t)NE * 4);
    int*   row_start  = (int*)alloc((size_t)(NN + 1) * 4);
    int*   deg        = (int*)alloc((size_t)NN * 4);
    int*   cursor     = (int*)alloc((size_t)NN * 4);
    float* hs2        = (float*)alloc((size_t)NN * 2 * 4);
    float* hd2        = (float*)alloc((size_t)NN * 2 * 4);
    (void)ws_size; (void)n_in; (void)in_sizes; (void)out_size;

    hipMemsetAsync(deg, 0, (size_t)NN * 4, stream);
    hipMemsetAsync(cursor, 0, (size_t)NN * 4, stream);

    dim3 ggrid((NN + 63) / 64, 2);
    gemm_proj<<<ggrid, 256, 0, stream>>>(feat, W1s, b1s, hs1, W1d, b1d, hd1, NN);

    const int eb = (NE + 255) / 256;
    count_deg<<<eb, 256, 0, stream>>>(dst, deg);
    scan_deg<<<1, 1024, 0, stream>>>(deg, row_start);
    scatter_src<<<eb, 256, 0, stream>>>(src, dst, row_start, cursor, src_sorted);

    gat1_fused<<<NN, 256, 0, stream>>>(hs1, hd1, attn1, src_sorted, row_start,
                                       W2s, b2s, W2d, b2d, hs2, hd2);

    node2_kernel<<<(NN + 3) / 4, 256, 0, stream>>>(hs2, hd2, attn2, src_sorted,
                                                   row_start, out);
}

// Round 4
// 558.404 us; speedup vs baseline: 1.3921x; 1.2753x over previous
//
#include <hip/hip_runtime.h>
#include <math.h>

#define NN 50000
#define NE 800000
#define NEG 0.2f

// ---------- fused dual GEMM: out[N,256] = feat[N,128] @ W + b  (gridDim.y picks W1s/W1d)
__global__ __launch_bounds__(256) void gemm_proj(
    const float* __restrict__ feat,
    const float* __restrict__ Wa, const float* __restrict__ ba, float* __restrict__ outa,
    const float* __restrict__ Wb, const float* __restrict__ bb, float* __restrict__ outb,
    int n_rows)
{
    const float* W = blockIdx.y ? Wb : Wa;
    const float* bv = blockIdx.y ? bb : ba;
    float* out = blockIdx.y ? outb : outa;

    __shared__ float fT[64][128];
    __shared__ float wT[16][256];

    const int row0 = blockIdx.x * 64;
    const int tid = threadIdx.x;

    {
        const float4* f4 = reinterpret_cast<const float4*>(feat);
#pragma unroll
        for (int p = 0; p < 8; ++p) {
            int idx = p * 256 + tid;
            int r = idx >> 5, c4 = idx & 31;
            int gr = row0 + r;
            float4 v = (gr < n_rows) ? f4[(size_t)gr * 32 + c4]
                                     : make_float4(0.f, 0.f, 0.f, 0.f);
            *reinterpret_cast<float4*>(&fT[r][c4 * 4]) = v;
        }
    }

    const int tm = tid >> 5;
    const int tn = tid & 31;
    float acc[8][8];
#pragma unroll
    for (int ri = 0; ri < 8; ++ri)
#pragma unroll
        for (int ci = 0; ci < 8; ++ci) acc[ri][ci] = 0.0f;

    const float4* W4 = reinterpret_cast<const float4*>(W);
    for (int k0 = 0; k0 < 128; k0 += 16) {
        __syncthreads();
#pragma unroll
        for (int p = 0; p < 4; ++p) {
            int idx = p * 256 + tid;
            int r = idx >> 6, c4 = idx & 63;
            *reinterpret_cast<float4*>(&wT[r][c4 * 4]) = W4[(size_t)(k0 + r) * 64 + c4];
        }
        __syncthreads();
#pragma unroll
        for (int kk = 0; kk < 16; ++kk) {
            float a[8], w[8];
#pragma unroll
            for (int ri = 0; ri < 8; ++ri) a[ri] = fT[tm + ri * 8][k0 + kk];
#pragma unroll
            for (int ci = 0; ci < 8; ++ci) w[ci] = wT[kk][tn + ci * 32];
#pragma unroll
            for (int ri = 0; ri < 8; ++ri)
#pragma unroll
                for (int ci = 0; ci < 8; ++ci)
                    acc[ri][ci] = fmaf(a[ri], w[ci], acc[ri][ci]);
        }
    }
#pragma unroll
    for (int ri = 0; ri < 8; ++ri) {
        int row = row0 + tm + ri * 8;
        if (row < n_rows) {
#pragma unroll
            for (int ci = 0; ci < 8; ++ci) {
                int col = tn + ci * 32;
                out[(size_t)row * 256 + col] = acc[ri][ci] + bv[col];
            }
        }
    }
}

// ---------------- CSR build ----------------
__global__ void count_deg(const int* __restrict__ dst, int* __restrict__ deg)
{
    int e = blockIdx.x * blockDim.x + threadIdx.x;
    if (e < NE) atomicAdd(&deg[dst[e]], 1);
}

__global__ __launch_bounds__(1024) void scan_deg(const int* __restrict__ deg,
                                                 int* __restrict__ row_start)
{
    __shared__ int part[1024];
    const int tid = threadIdx.x;
    const int CH = (NN + 1023) / 1024;
    int begin = tid * CH;
    int end_ = begin + CH; if (end_ > NN) end_ = NN;
    int s = 0;
    for (int i = begin; i < end_; ++i) s += deg[i];
    part[tid] = s;
    __syncthreads();
    for (int off = 1; off < 1024; off <<= 1) {
        int v = (tid >= off) ? part[tid - off] : 0;
        __syncthreads();
        part[tid] += v;
        __syncthreads();
    }
    int base = (tid > 0) ? part[tid - 1] : 0;
    for (int i = begin; i < end_; ++i) {
        row_start[i] = base;
        base += deg[i];
    }
    if (tid == 1023) row_start[NN] = part[1023];
}

__global__ void scatter_src(const int* __restrict__ src, const int* __restrict__ dst,
                            const int* __restrict__ row_start,
                            int* __restrict__ cursor,
                            int* __restrict__ src_sorted, int* __restrict__ dst_sorted)
{
    int e = blockIdx.x * blockDim.x + threadIdx.x;
    if (e < NE) {
        int d = dst[e];
        int pos = row_start[d] + atomicAdd(&cursor[d], 1);
        src_sorted[pos] = src[e];
        dst_sorted[pos] = d;
    }
}

// ---- Phase A: scores[h][i] for CSR position i. 16 lanes per (edge,head), float4/lane.
__global__ __launch_bounds__(256) void gat1_scores(
    const float* __restrict__ hs, const float* __restrict__ hd,
    const float* __restrict__ attn,
    const int* __restrict__ src_sorted, const int* __restrict__ dst_sorted,
    float* __restrict__ score)
{
    const int h = threadIdx.x >> 6;      // head (wave)
    const int lane = threadIdx.x & 63;
    const int g = lane >> 4;             // edge sub-group 0..3
    const int q = lane & 15;             // dim quad
    const float4 a4 = *reinterpret_cast<const float4*>(&attn[h * 64 + q * 4]);
    const int e_base = blockIdx.x * 16;  // NE % 16 == 0

#pragma unroll
    for (int it = 0; it < 4; ++it) {
        const int e = e_base + it * 4 + g;
        const int s = src_sorted[e];
        const int d = dst_sorted[e];
        const float4 x = *reinterpret_cast<const float4*>(&hs[(size_t)s * 256 + h * 64 + q * 4]);
        const float4 y = *reinterpret_cast<const float4*>(&hd[(size_t)d * 256 + h * 64 + q * 4]);
        float t0 = x.x + y.x; t0 = fmaxf(t0, NEG * t0);
        float t1 = x.y + y.y; t1 = fmaxf(t1, NEG * t1);
        float t2 = x.z + y.z; t2 = fmaxf(t2, NEG * t2);
        float t3 = x.w + y.w; t3 = fmaxf(t3, NEG * t3);
        float p = t0 * a4.x;
        p = fmaf(t1, a4.y, p);
        p = fmaf(t2, a4.z, p);
        p = fmaf(t3, a4.w, p);
        p += __shfl_xor(p, 1);
        p += __shfl_xor(p, 2);
        p += __shfl_xor(p, 4);
        p += __shfl_xor(p, 8);
        if (q == 0) score[(size_t)h * NE + e] = p;
    }
}

// ---- Phase B: block=node, wave=head, lane=dim. No per-edge cross-lane ops/exp.
__global__ __launch_bounds__(256) void gat1_aggregate(
    const float* __restrict__ hs, const float* __restrict__ score,
    const int* __restrict__ src_sorted, const int* __restrict__ row_start,
    const float* __restrict__ W2s, const float* __restrict__ b2s,
    const float* __restrict__ W2d, const float* __restrict__ b2d,
    float* __restrict__ hs2, float* __restrict__ hd2)
{
    __shared__ float2 wl[4][64];
    __shared__ float red[4][4];
    const int n = blockIdx.x;
    const int h = threadIdx.x >> 6;
    const int lane = threadIdx.x & 63;
    const int fi = threadIdx.x;
    const int beg = row_start[n], end_ = row_start[n + 1];
    const float* __restrict__ sc_h = score + (size_t)h * NE;

    // pass 1: running max over this node's scores (coalesced)
    float m = -INFINITY;
    for (int i = beg + lane; i < end_; i += 64) m = fmaxf(m, sc_h[i]);
#pragma unroll
    for (int off = 32; off; off >>= 1) m = fmaxf(m, __shfl_xor(m, off));

    // pass 2: per 64-edge chunk: w=exp(sc-m) into LDS, then gather-fma inner loop
    float den = 0.0f, acc = 0.0f;
    for (int cb = beg; cb < end_; cb += 64) {
        const int cnt = min(64, end_ - cb);
        if (lane < cnt) {
            float w = __expf(sc_h[cb + lane] - m);
            den += w;
            int s = src_sorted[cb + lane];
            wl[h][lane] = make_float2(w, __int_as_float(s));
        }
        for (int j = 0; j < cnt; ++j) {
            float2 ws = wl[h][j];                       // uniform ds_read (broadcast)
            int s = __float_as_int(ws.y);
            acc = fmaf(ws.x, hs[(size_t)s * 256 + fi], acc);
        }
    }
#pragma unroll
    for (int off = 32; off; off >>= 1) den += __shfl_xor(den, off);

    float o = (den > 0.0f) ? acc / den : 0.0f;
    o = (o > 0.0f) ? o : __expf(o) - 1.0f;              // ELU fused

    // fused layer-2 projection: hs2/hd2[n] = h1[n] @ W2{s,d} + b2{s,d}
    float s0 = o * W2s[fi * 2 + 0], s1 = o * W2s[fi * 2 + 1];
    float d0 = o * W2d[fi * 2 + 0], d1 = o * W2d[fi * 2 + 1];
#pragma unroll
    for (int off = 32; off; off >>= 1) {
        s0 += __shfl_xor(s0, off);
        s1 += __shfl_xor(s1, off);
        d0 += __shfl_xor(d0, off);
        d1 += __shfl_xor(d1, off);
    }
    if (lane == 0) {
        red[h][0] = s0; red[h][1] = s1; red[h][2] = d0; red[h][3] = d1;
    }
    __syncthreads();
    if (threadIdx.x < 2) {
        int c = threadIdx.x;
        hs2[(size_t)n * 2 + c] = red[0][c] + red[1][c] + red[2][c] + red[3][c] + b2s[c];
    } else if (threadIdx.x >= 64 && threadIdx.x < 66) {
        int c = threadIdx.x - 64;
        hd2[(size_t)n * 2 + c] =
            red[0][2 + c] + red[1][2 + c] + red[2][2 + c] + red[3][2 + c] + b2d[c];
    }
}

// ---------------- Layer-2: wave per node, lane per edge ----------------
__global__ __launch_bounds__(256) void node2_kernel(
    const float* __restrict__ hs2, const float* __restrict__ hd2,
    const float* __restrict__ attn2, const int* __restrict__ src_sorted,
    const int* __restrict__ row_start, float* __restrict__ out)
{
    const int n = blockIdx.x * 4 + (threadIdx.x >> 6);
    const int lane = threadIdx.x & 63;
    if (n >= NN) return;
    const float a0 = attn2[0], a1 = attn2[1];
    const float h0 = hd2[n * 2 + 0], h1v = hd2[n * 2 + 1];
    const int beg = row_start[n], end_ = row_start[n + 1];
    float m = -INFINITY, den = 0.0f, A0 = 0.0f, A1 = 0.0f;
    for (int i = beg + lane; i < end_; i += 64) {
        const int s = src_sorted[i];
        float x0 = hs2[s * 2 + 0], x1 = hs2[s * 2 + 1];
        float t0 = x0 + h0;  t0 = fmaxf(t0, NEG * t0);
        float t1 = x1 + h1v; t1 = fmaxf(t1, NEG * t1);
        float p = fmaf(t0, a0, t1 * a1);
        float mn = fmaxf(m, p);
        float c = __expf(m - mn);
        float w = __expf(p - mn);
        den = den * c + w;
        A0 = A0 * c + w * x0;
        A1 = A1 * c + w * x1;
        m = mn;
    }
#pragma unroll
    for (int off = 1; off < 64; off <<= 1) {
        float m2 = __shfl_xor(m, off);
        float d2 = __shfl_xor(den, off);
        float b0 = __shfl_xor(A0, off);
        float b1 = __shfl_xor(A1, off);
        float mn = fmaxf(m, m2);
        float c1 = (m < mn) ? __expf(m - mn) : 1.0f;
        float c2 = (m2 < mn) ? __expf(m2 - mn) : 1.0f;
        den = den * c1 + d2 * c2;
        A0 = A0 * c1 + b0 * c2;
        A1 = A1 * c1 + b1 * c2;
        m = mn;
    }
    if (lane == 0) {
        out[n * 2 + 0] = (den > 0.0f) ? A0 / den : 0.0f;
        out[n * 2 + 1] = (den > 0.0f) ? A1 / den : 0.0f;
    }
}

// ---------------- launch ----------------
extern "C" void kernel_launch(void* const* d_in, const int* in_sizes, int n_in,
                              void* d_out, int out_size, void* d_ws, size_t ws_size,
                              hipStream_t stream)
{
    const float* feat  = (const float*)d_in[0];
    const int*   src   = (const int*)d_in[1];
    const int*   dst   = (const int*)d_in[2];
    const float* W1s   = (const float*)d_in[3];
    const float* b1s   = (const float*)d_in[4];
    const float* W1d   = (const float*)d_in[5];
    const float* b1d   = (const float*)d_in[6];
    const float* attn1 = (const float*)d_in[7];
    const float* W2s   = (const float*)d_in[8];
    const float* b2s   = (const float*)d_in[9];
    const float* W2d   = (const float*)d_in[10];
    const float* b2d   = (const float*)d_in[11];
    const float* attn2 = (const float*)d_in[12];
    float* out = (float*)d_out;

    char* ws = (char*)d_ws;
    size_t off = 0;
    auto alloc = [&](size_t bytes) {
        char* p = ws + off;
        off += (bytes + 255) & ~size_t(255);
        return p;
    };
    float* hs1        = (float*)alloc((size_t)NN * 256 * 4);
    float* hd1        = (float*)alloc((size_t)NN * 256 * 4);
    float* score      = (float*)alloc((size_t)4 * NE * 4);
    int*   src_sorted = (int*)alloc((size_t)NE * 4);
    int*   dst_sorted = (int*)alloc((size_t)NE * 4);
    int*   row_start  = (int*)alloc((size_t)(NN + 1) * 4);
    int*   deg        = (int*)alloc((size_t)NN * 4);
    int*   cursor     = (int*)alloc((size_t)NN * 4);
    float* hs2        = (float*)alloc((size_t)NN * 2 * 4);
    float* hd2        = (float*)alloc((size_t)NN * 2 * 4);
    (void)ws_size; (void)n_in; (void)in_sizes; (void)out_size;

    hipMemsetAsync(deg, 0, (size_t)NN * 4, stream);
    hipMemsetAsync(cursor, 0, (size_t)NN * 4, stream);

    dim3 ggrid((NN + 63) / 64, 2);
    gemm_proj<<<ggrid, 256, 0, stream>>>(feat, W1s, b1s, hs1, W1d, b1d, hd1, NN);

    const int eb = (NE + 255) / 256;
    count_deg<<<eb, 256, 0, stream>>>(dst, deg);
    scan_deg<<<1, 1024, 0, stream>>>(deg, row_start);
    scatter_src<<<eb, 256, 0, stream>>>(src, dst, row_start, cursor, src_sorted, dst_sorted);

    gat1_scores<<<NE / 16, 256, 0, stream>>>(hs1, hd1, attn1, src_sorted, dst_sorted, score);

    gat1_aggregate<<<NN, 256, 0, stream>>>(hs1, score, src_sorted, row_start,
                                           W2s, b2s, W2d, b2d, hs2, hd2);

    node2_kernel<<<(NN + 3) / 4, 256, 0, stream>>>(hs2, hd2, attn2, src_sorted,
                                                   row_start, out);
}

// Round 5
// 421.196 us; speedup vs baseline: 1.8456x; 1.3258x over previous
//
#include <hip/hip_runtime.h>
#include <math.h>

#define NN 50000
#define NE 800000
#define NEG 0.2f
#define NB 196  // ceil(NN/256)

// ---------- fused dual GEMM: out[N,256] = feat[N,128] @ W + b  (gridDim.y picks W1s/W1d)
__global__ __launch_bounds__(256) void gemm_proj(
    const float* __restrict__ feat,
    const float* __restrict__ Wa, const float* __restrict__ ba, float* __restrict__ outa,
    const float* __restrict__ Wb, const float* __restrict__ bb, float* __restrict__ outb,
    int n_rows)
{
    const float* W = blockIdx.y ? Wb : Wa;
    const float* bv = blockIdx.y ? bb : ba;
    float* out = blockIdx.y ? outb : outa;

    __shared__ float fT[64][128];
    __shared__ float wT[16][256];

    const int row0 = blockIdx.x * 64;
    const int tid = threadIdx.x;

    {
        const float4* f4 = reinterpret_cast<const float4*>(feat);
#pragma unroll
        for (int p = 0; p < 8; ++p) {
            int idx = p * 256 + tid;
            int r = idx >> 5, c4 = idx & 31;
            int gr = row0 + r;
            float4 v = (gr < n_rows) ? f4[(size_t)gr * 32 + c4]
                                     : make_float4(0.f, 0.f, 0.f, 0.f);
            *reinterpret_cast<float4*>(&fT[r][c4 * 4]) = v;
        }
    }

    const int tm = tid >> 5;
    const int tn = tid & 31;
    float acc[8][8];
#pragma unroll
    for (int ri = 0; ri < 8; ++ri)
#pragma unroll
        for (int ci = 0; ci < 8; ++ci) acc[ri][ci] = 0.0f;

    const float4* W4 = reinterpret_cast<const float4*>(W);
    for (int k0 = 0; k0 < 128; k0 += 16) {
        __syncthreads();
#pragma unroll
        for (int p = 0; p < 4; ++p) {
            int idx = p * 256 + tid;
            int r = idx >> 6, c4 = idx & 63;
            *reinterpret_cast<float4*>(&wT[r][c4 * 4]) = W4[(size_t)(k0 + r) * 64 + c4];
        }
        __syncthreads();
#pragma unroll
        for (int kk = 0; kk < 16; ++kk) {
            float a[8], w[8];
#pragma unroll
            for (int ri = 0; ri < 8; ++ri) a[ri] = fT[tm + ri * 8][k0 + kk];
#pragma unroll
            for (int ci = 0; ci < 8; ++ci) w[ci] = wT[kk][tn + ci * 32];
#pragma unroll
            for (int ri = 0; ri < 8; ++ri)
#pragma unroll
                for (int ci = 0; ci < 8; ++ci)
                    acc[ri][ci] = fmaf(a[ri], w[ci], acc[ri][ci]);
        }
    }
#pragma unroll
    for (int ri = 0; ri < 8; ++ri) {
        int row = row0 + tm + ri * 8;
        if (row < n_rows) {
#pragma unroll
            for (int ci = 0; ci < 8; ++ci) {
                int col = tn + ci * 32;
                out[(size_t)row * 256 + col] = acc[ri][ci] + bv[col];
            }
        }
    }
}

// ---------------- CSR build ----------------
__global__ void count_deg(const int* __restrict__ dst, int* __restrict__ deg)
{
    int e = blockIdx.x * blockDim.x + threadIdx.x;
    if (e < NE) atomicAdd(&deg[dst[e]], 1);
}

__global__ __launch_bounds__(256) void deg_blocksum(const int* __restrict__ deg,
                                                    int* __restrict__ bsum)
{
    int i = blockIdx.x * 256 + threadIdx.x;
    int v = (i < NN) ? deg[i] : 0;
#pragma unroll
    for (int off = 32; off; off >>= 1) v += __shfl_xor(v, off);
    __shared__ int ws[4];
    if ((threadIdx.x & 63) == 0) ws[threadIdx.x >> 6] = v;
    __syncthreads();
    if (threadIdx.x == 0) bsum[blockIdx.x] = ws[0] + ws[1] + ws[2] + ws[3];
}

__global__ __launch_bounds__(256) void scan_bsum(int* __restrict__ bsum)
{
    __shared__ int tmp[256];
    int t = threadIdx.x;
    int orig = (t < NB) ? bsum[t] : 0;
    tmp[t] = orig;
    __syncthreads();
    for (int off = 1; off < 256; off <<= 1) {
        int v = (t >= off) ? tmp[t - off] : 0;
        __syncthreads();
        tmp[t] += v;
        __syncthreads();
    }
    if (t < NB) bsum[t] = tmp[t] - orig;  // exclusive prefix
}

__global__ __launch_bounds__(256) void write_rows(const int* __restrict__ deg,
                                                  const int* __restrict__ bpre,
                                                  int* __restrict__ row_start)
{
    int i = blockIdx.x * 256 + threadIdx.x;
    int d = (i < NN) ? deg[i] : 0;
    int lane = threadIdx.x & 63, w = threadIdx.x >> 6;
    int x = d;
#pragma unroll
    for (int off = 1; off < 64; off <<= 1) {
        int v = __shfl_up(x, off);
        if (lane >= off) x += v;
    }
    __shared__ int wsum[4];
    if (lane == 63) wsum[w] = x;
    __syncthreads();
    int woff = 0;
#pragma unroll
    for (int k = 0; k < 4; ++k)
        if (k < w) woff += wsum[k];
    if (i < NN) row_start[i] = bpre[blockIdx.x] + woff + x - d;
    if (blockIdx.x == 0 && threadIdx.x == 0) row_start[NN] = NE;
}

__global__ void scatter_src(const int* __restrict__ src, const int* __restrict__ dst,
                            const int* __restrict__ row_start,
                            int* __restrict__ cursor, int* __restrict__ src_sorted)
{
    int e = blockIdx.x * blockDim.x + threadIdx.x;
    if (e < NE) {
        int d = dst[e];
        int pos = row_start[d] + atomicAdd(&cursor[d], 1);
        src_sorted[pos] = src[e];
    }
}

// ---- Layer-1 fully fused: block = node, wave = whole edges, lane = 4 dims of 256.
//      Chunked two-pass online softmax + fused ELU + fused layer-2 projection.
__global__ __launch_bounds__(256) void gat1_fused(
    const float* __restrict__ hs, const float* __restrict__ hd,
    const float* __restrict__ attn, const int* __restrict__ src_sorted,
    const int* __restrict__ row_start,
    const float* __restrict__ W2s, const float* __restrict__ b2s,
    const float* __restrict__ W2d, const float* __restrict__ b2d,
    float* __restrict__ hs2, float* __restrict__ hd2)
{
    __shared__ float sc[4 * 65];     // [head][edge-in-chunk], padded
    __shared__ float wl[4 * 65];
    __shared__ float cmw[4][4];      // [wave][head] chunk maxima
    __shared__ float den_lds[4];
    __shared__ float4 accs[4][64];   // cross-wave accumulator merge

    const int n = blockIdx.x;
    const int tid = threadIdx.x;
    const int w = tid >> 6;          // wave id; also head for weight/den phase
    const int lane = tid & 63;
    const int q = lane & 15;
    const int hh = lane >> 4;        // head owning this lane's 4 dims
    const int beg = row_start[n], end_ = row_start[n + 1];

    const float4 a4 = *reinterpret_cast<const float4*>(&attn[lane * 4]);
    const float4 y4 = *reinterpret_cast<const float4*>(&hd[(size_t)n * 256 + lane * 4]);

    float m = -INFINITY;   // running max for head hh (acc rescale)
    float m2 = -INFINITY;  // running max for head w  (den rescale)
    float den = 0.0f;
    float4 acc = make_float4(0.f, 0.f, 0.f, 0.f);

    for (int cb = beg; cb < end_; cb += 64) {
        const int cnt = min(64, end_ - cb);

        // ---- pass 1: scores for this wave's edges (4 heads per edge at once) ----
        float cm = -INFINITY;
        for (int jj = w; jj < cnt; jj += 4) {
            const int s = __builtin_amdgcn_readfirstlane(src_sorted[cb + jj]);
            const float4 x = *reinterpret_cast<const float4*>(
                &hs[(size_t)s * 256 + lane * 4]);
            float t0 = x.x + y4.x; t0 = fmaxf(t0, NEG * t0);
            float t1 = x.y + y4.y; t1 = fmaxf(t1, NEG * t1);
            float t2 = x.z + y4.z; t2 = fmaxf(t2, NEG * t2);
            float t3 = x.w + y4.w; t3 = fmaxf(t3, NEG * t3);
            float p = t0 * a4.x;
            p = fmaf(t1, a4.y, p);
            p = fmaf(t2, a4.z, p);
            p = fmaf(t3, a4.w, p);
            p += __shfl_xor(p, 1);
            p += __shfl_xor(p, 2);
            p += __shfl_xor(p, 4);
            p += __shfl_xor(p, 8);          // all 16 lanes hold head-hh score
            if (q == 0) sc[hh * 65 + jj] = p;
            cm = fmaxf(cm, p);
        }
        if (q == 0) cmw[w][hh] = cm;
        __syncthreads();

        // ---- online max update + rescale (per-chunk, not per-edge) ----
        float gA = fmaxf(fmaxf(cmw[0][hh], cmw[1][hh]), fmaxf(cmw[2][hh], cmw[3][hh]));
        float mnA = fmaxf(m, gA);
        float rsA = __expf(m - mnA);        // m=-inf first chunk -> 0 (mnA finite)
        acc.x *= rsA; acc.y *= rsA; acc.z *= rsA; acc.w *= rsA;
        m = mnA;
        float gB = fmaxf(fmaxf(cmw[0][w], cmw[1][w]), fmaxf(cmw[2][w], cmw[3][w]));
        float mnB = fmaxf(m2, gB);
        den *= __expf(m2 - mnB);
        m2 = mnB;

        // ---- weights: thread (head=w, edge=lane) ----
        if (lane < cnt) {
            float wv = __expf(sc[w * 65 + lane] - m2);
            den += wv;
            wl[w * 65 + lane] = wv;
        }
        __syncthreads();

        // ---- pass 2: weighted aggregation (re-gather is L2-hot) ----
        for (int jj = w; jj < cnt; jj += 4) {
            const int s = __builtin_amdgcn_readfirstlane(src_sorted[cb + jj]);
            const float wv = wl[hh * 65 + jj];
            const float4 x = *reinterpret_cast<const float4*>(
                &hs[(size_t)s * 256 + lane * 4]);
            acc.x = fmaf(wv, x.x, acc.x);
            acc.y = fmaf(wv, x.y, acc.y);
            acc.z = fmaf(wv, x.z, acc.z);
            acc.w = fmaf(wv, x.w, acc.w);
        }
        // no barrier needed here: next pass-1 touches sc/cmw only, and the
        // next barrier precedes any wl overwrite
    }

    // ---- merge across waves ----
#pragma unroll
    for (int off = 32; off; off >>= 1) den += __shfl_xor(den, off);
    if (lane == 0) den_lds[w] = den;
    accs[w][lane] = acc;
    __syncthreads();

    if (w == 0) {
        float4 o = accs[0][lane];
        const float4 o1 = accs[1][lane], o2 = accs[2][lane], o3 = accs[3][lane];
        o.x += o1.x + o2.x + o3.x;
        o.y += o1.y + o2.y + o3.y;
        o.z += o1.z + o2.z + o3.z;
        o.w += o1.w + o2.w + o3.w;
        const float dn = den_lds[hh];
        const float inv = (dn > 0.0f) ? 1.0f / dn : 0.0f;
        o.x *= inv; o.y *= inv; o.z *= inv; o.w *= inv;
        // ELU
        o.x = (o.x > 0.0f) ? o.x : __expf(o.x) - 1.0f;
        o.y = (o.y > 0.0f) ? o.y : __expf(o.y) - 1.0f;
        o.z = (o.z > 0.0f) ? o.z : __expf(o.z) - 1.0f;
        o.w = (o.w > 0.0f) ? o.w : __expf(o.w) - 1.0f;
        // layer-2 projection: rows 4*lane..4*lane+3 of W2 [256][2]
        const float4 wsa = *reinterpret_cast<const float4*>(&W2s[lane * 8]);
        const float4 wsb = *reinterpret_cast<const float4*>(&W2s[lane * 8 + 4]);
        const float4 wda = *reinterpret_cast<const float4*>(&W2d[lane * 8]);
        const float4 wdb = *reinterpret_cast<const float4*>(&W2d[lane * 8 + 4]);
        float ps0 = o.x * wsa.x + o.y * wsa.z + o.z * wsb.x + o.w * wsb.z;
        float ps1 = o.x * wsa.y + o.y * wsa.w + o.z * wsb.y + o.w * wsb.w;
        float pd0 = o.x * wda.x + o.y * wda.z + o.z * wdb.x + o.w * wdb.z;
        float pd1 = o.x * wda.y + o.y * wda.w + o.z * wdb.y + o.w * wdb.w;
#pragma unroll
        for (int off = 32; off; off >>= 1) {
            ps0 += __shfl_xor(ps0, off);
            ps1 += __shfl_xor(ps1, off);
            pd0 += __shfl_xor(pd0, off);
            pd1 += __shfl_xor(pd1, off);
        }
        if (lane == 0) {
            hs2[(size_t)n * 2 + 0] = ps0 + b2s[0];
            hs2[(size_t)n * 2 + 1] = ps1 + b2s[1];
            hd2[(size_t)n * 2 + 0] = pd0 + b2d[0];
            hd2[(size_t)n * 2 + 1] = pd1 + b2d[1];
        }
    }
}

// ---------------- Layer-2: wave per node, lane per edge ----------------
__global__ __launch_bounds__(256) void node2_kernel(
    const float* __restrict__ hs2, const float* __restrict__ hd2,
    const float* __restrict__ attn2, const int* __restrict__ src_sorted,
    const int* __restrict__ row_start, float* __restrict__ out)
{
    const int n = blockIdx.x * 4 + (threadIdx.x >> 6);
    const int lane = threadIdx.x & 63;
    if (n >= NN) return;
    const float a0 = attn2[0], a1 = attn2[1];
    const float h0 = hd2[n * 2 + 0], h1v = hd2[n * 2 + 1];
    const int beg = row_start[n], end_ = row_start[n + 1];
    float m = -INFINITY, den = 0.0f, A0 = 0.0f, A1 = 0.0f;
    for (int i = beg + lane; i < end_; i += 64) {
        const int s = src_sorted[i];
        float x0 = hs2[s * 2 + 0], x1 = hs2[s * 2 + 1];
        float t0 = x0 + h0;  t0 = fmaxf(t0, NEG * t0);
        float t1 = x1 + h1v; t1 = fmaxf(t1, NEG * t1);
        float p = fmaf(t0, a0, t1 * a1);
        float mn = fmaxf(m, p);
        float c = __expf(m - mn);
        float w = __expf(p - mn);
        den = den * c + w;
        A0 = A0 * c + w * x0;
        A1 = A1 * c + w * x1;
        m = mn;
    }
#pragma unroll
    for (int off = 1; off < 64; off <<= 1) {
        float m2 = __shfl_xor(m, off);
        float d2 = __shfl_xor(den, off);
        float b0 = __shfl_xor(A0, off);
        float b1 = __shfl_xor(A1, off);
        float mn = fmaxf(m, m2);
        float c1 = (m < mn) ? __expf(m - mn) : 1.0f;
        float c2 = (m2 < mn) ? __expf(m2 - mn) : 1.0f;
        den = den * c1 + d2 * c2;
        A0 = A0 * c1 + b0 * c2;
        A1 = A1 * c1 + b1 * c2;
        m = mn;
    }
    if (lane == 0) {
        out[n * 2 + 0] = (den > 0.0f) ? A0 / den : 0.0f;
        out[n * 2 + 1] = (den > 0.0f) ? A1 / den : 0.0f;
    }
}

// ---------------- launch ----------------
extern "C" void kernel_launch(void* const* d_in, const int* in_sizes, int n_in,
                              void* d_out, int out_size, void* d_ws, size_t ws_size,
                              hipStream_t stream)
{
    const float* feat  = (const float*)d_in[0];
    const int*   src   = (const int*)d_in[1];
    const int*   dst   = (const int*)d_in[2];
    const float* W1s   = (const float*)d_in[3];
    const float* b1s   = (const float*)d_in[4];
    const float* W1d   = (const float*)d_in[5];
    const float* b1d   = (const float*)d_in[6];
    const float* attn1 = (const float*)d_in[7];
    const float* W2s   = (const float*)d_in[8];
    const float* b2s   = (const float*)d_in[9];
    const float* W2d   = (const float*)d_in[10];
    const float* b2d   = (const float*)d_in[11];
    const float* attn2 = (const float*)d_in[12];
    float* out = (float*)d_out;

    char* ws = (char*)d_ws;
    size_t off = 0;
    auto alloc = [&](size_t bytes) {
        char* p = ws + off;
        off += (bytes + 255) & ~size_t(255);
        return p;
    };
    float* hs1        = (float*)alloc((size_t)NN * 256 * 4);
    float* hd1        = (float*)alloc((size_t)NN * 256 * 4);
    int*   src_sorted = (int*)alloc((size_t)NE * 4);
    int*   row_start  = (int*)alloc((size_t)(NN + 1) * 4);
    int*   deg        = (int*)alloc((size_t)NN * 4);
    int*   cursor     = (int*)alloc((size_t)NN * 4);
    int*   bsum       = (int*)alloc((size_t)NB * 4);
    float* hs2        = (float*)alloc((size_t)NN * 2 * 4);
    float* hd2        = (float*)alloc((size_t)NN * 2 * 4);
    (void)ws_size; (void)n_in; (void)in_sizes; (void)out_size;

    hipMemsetAsync(deg, 0, (size_t)NN * 4, stream);
    hipMemsetAsync(cursor, 0, (size_t)NN * 4, stream);

    dim3 ggrid((NN + 63) / 64, 2);
    gemm_proj<<<ggrid, 256, 0, stream>>>(feat, W1s, b1s, hs1, W1d, b1d, hd1, NN);

    const int eb = (NE + 255) / 256;
    count_deg<<<eb, 256, 0, stream>>>(dst, deg);
    deg_blocksum<<<NB, 256, 0, stream>>>(deg, bsum);
    scan_bsum<<<1, 256, 0, stream>>>(bsum);
    write_rows<<<NB, 256, 0, stream>>>(deg, bsum, row_start);
    scatter_src<<<eb, 256, 0, stream>>>(src, dst, row_start, cursor, src_sorted);

    gat1_fused<<<NN, 256, 0, stream>>>(hs1, hd1, attn1, src_sorted, row_start,
                                       W2s, b2s, W2d, b2d, hs2, hd2);

    node2_kernel<<<(NN + 3) / 4, 256, 0, stream>>>(hs2, hd2, attn2, src_sorted,
                                                   row_start, out);
}

// Round 6
// 358.592 us; speedup vs baseline: 2.1678x; 1.1746x over previous
//
#include <hip/hip_runtime.h>
#include <math.h>

#define NN 50000
#define NE 800000
#define NEG 0.2f
#define NB 196  // ceil(NN/256)

// ---------- fused dual GEMM: out[N,256] = feat[N,128] @ W + b  (gridDim.y picks W1s/W1d)
__global__ __launch_bounds__(256) void gemm_proj(
    const float* __restrict__ feat,
    const float* __restrict__ Wa, const float* __restrict__ ba, float* __restrict__ outa,
    const float* __restrict__ Wb, const float* __restrict__ bb, float* __restrict__ outb,
    int n_rows)
{
    const float* W = blockIdx.y ? Wb : Wa;
    const float* bv = blockIdx.y ? bb : ba;
    float* out = blockIdx.y ? outb : outa;

    __shared__ float fT[64][128];
    __shared__ float wT[16][256];

    const int row0 = blockIdx.x * 64;
    const int tid = threadIdx.x;

    {
        const float4* f4 = reinterpret_cast<const float4*>(feat);
#pragma unroll
        for (int p = 0; p < 8; ++p) {
            int idx = p * 256 + tid;
            int r = idx >> 5, c4 = idx & 31;
            int gr = row0 + r;
            float4 v = (gr < n_rows) ? f4[(size_t)gr * 32 + c4]
                                     : make_float4(0.f, 0.f, 0.f, 0.f);
            *reinterpret_cast<float4*>(&fT[r][c4 * 4]) = v;
        }
    }

    const int tm = tid >> 5;
    const int tn = tid & 31;
    float acc[8][8];
#pragma unroll
    for (int ri = 0; ri < 8; ++ri)
#pragma unroll
        for (int ci = 0; ci < 8; ++ci) acc[ri][ci] = 0.0f;

    const float4* W4 = reinterpret_cast<const float4*>(W);
    for (int k0 = 0; k0 < 128; k0 += 16) {
        __syncthreads();
#pragma unroll
        for (int p = 0; p < 4; ++p) {
            int idx = p * 256 + tid;
            int r = idx >> 6, c4 = idx & 63;
            *reinterpret_cast<float4*>(&wT[r][c4 * 4]) = W4[(size_t)(k0 + r) * 64 + c4];
        }
        __syncthreads();
#pragma unroll
        for (int kk = 0; kk < 16; ++kk) {
            float a[8], w[8];
#pragma unroll
            for (int ri = 0; ri < 8; ++ri) a[ri] = fT[tm + ri * 8][k0 + kk];
#pragma unroll
            for (int ci = 0; ci < 8; ++ci) w[ci] = wT[kk][tn + ci * 32];
#pragma unroll
            for (int ri = 0; ri < 8; ++ri)
#pragma unroll
                for (int ci = 0; ci < 8; ++ci)
                    acc[ri][ci] = fmaf(a[ri], w[ci], acc[ri][ci]);
        }
    }
#pragma unroll
    for (int ri = 0; ri < 8; ++ri) {
        int row = row0 + tm + ri * 8;
        if (row < n_rows) {
#pragma unroll
            for (int ci = 0; ci < 8; ++ci) {
                int col = tn + ci * 32;
                out[(size_t)row * 256 + col] = acc[ri][ci] + bv[col];
            }
        }
    }
}

// ---------------- CSR build ----------------
__global__ void count_deg(const int* __restrict__ dst, int* __restrict__ deg)
{
    int e = blockIdx.x * blockDim.x + threadIdx.x;
    if (e < NE) atomicAdd(&deg[dst[e]], 1);
}

__global__ __launch_bounds__(256) void deg_blocksum(const int* __restrict__ deg,
                                                    int* __restrict__ bsum)
{
    int i = blockIdx.x * 256 + threadIdx.x;
    int v = (i < NN) ? deg[i] : 0;
#pragma unroll
    for (int off = 32; off; off >>= 1) v += __shfl_xor(v, off);
    __shared__ int ws[4];
    if ((threadIdx.x & 63) == 0) ws[threadIdx.x >> 6] = v;
    __syncthreads();
    if (threadIdx.x == 0) bsum[blockIdx.x] = ws[0] + ws[1] + ws[2] + ws[3];
}

__global__ __launch_bounds__(256) void scan_bsum(int* __restrict__ bsum)
{
    __shared__ int tmp[256];
    int t = threadIdx.x;
    int orig = (t < NB) ? bsum[t] : 0;
    tmp[t] = orig;
    __syncthreads();
    for (int off = 1; off < 256; off <<= 1) {
        int v = (t >= off) ? tmp[t - off] : 0;
        __syncthreads();
        tmp[t] += v;
        __syncthreads();
    }
    if (t < NB) bsum[t] = tmp[t] - orig;  // exclusive prefix
}

__global__ __launch_bounds__(256) void write_rows(const int* __restrict__ deg,
                                                  const int* __restrict__ bpre,
                                                  int* __restrict__ row_start)
{
    int i = blockIdx.x * 256 + threadIdx.x;
    int d = (i < NN) ? deg[i] : 0;
    int lane = threadIdx.x & 63, w = threadIdx.x >> 6;
    int x = d;
#pragma unroll
    for (int off = 1; off < 64; off <<= 1) {
        int v = __shfl_up(x, off);
        if (lane >= off) x += v;
    }
    __shared__ int wsum[4];
    if (lane == 63) wsum[w] = x;
    __syncthreads();
    int woff = 0;
#pragma unroll
    for (int k = 0; k < 4; ++k)
        if (k < w) woff += wsum[k];
    if (i < NN) row_start[i] = bpre[blockIdx.x] + woff + x - d;
    if (blockIdx.x == 0 && threadIdx.x == 0) row_start[NN] = NE;
}

__global__ void scatter_src(const int* __restrict__ src, const int* __restrict__ dst,
                            const int* __restrict__ row_start,
                            int* __restrict__ cursor, int* __restrict__ src_sorted)
{
    int e = blockIdx.x * blockDim.x + threadIdx.x;
    if (e < NE) {
        int d = dst[e];
        int pos = row_start[d] + atomicAdd(&cursor[d], 1);
        src_sorted[pos] = src[e];
    }
}

// ---- Layer-1 fused, SINGLE PASS with defer-max: block=node, wave=edges, lane=4 dims.
//      Zero barriers in the edge loop; per-wave (m,den,acc) merged once at the end.
__global__ __launch_bounds__(256) void gat1_fused(
    const float* __restrict__ hs, const float* __restrict__ hd,
    const float* __restrict__ attn, const int* __restrict__ src_sorted,
    const int* __restrict__ row_start,
    const float* __restrict__ W2s, const float* __restrict__ b2s,
    const float* __restrict__ W2d, const float* __restrict__ b2d,
    float* __restrict__ hs2, float* __restrict__ hd2)
{
    __shared__ float mw[4][4];       // [wave][head] deferred max
    __shared__ float denw[4][4];     // [wave][head] denominator
    __shared__ float4 accs[4][64];   // [wave][lane] accumulators

    const int n = blockIdx.x;
    const int tid = threadIdx.x;
    const int w = tid >> 6;
    const int lane = tid & 63;
    const int q = lane & 15;
    const int hh = lane >> 4;        // head owning this lane's 4 dims
    const int beg = row_start[n], end_ = row_start[n + 1];

    const float4 a4 = *reinterpret_cast<const float4*>(&attn[lane * 4]);
    const float4 y4 = *reinterpret_cast<const float4*>(&hd[(size_t)n * 256 + lane * 4]);

    float m = -INFINITY, den = 0.0f;
    float4 acc = make_float4(0.f, 0.f, 0.f, 0.f);

    for (int i = beg + w; i < end_; i += 4) {
        const int s = __builtin_amdgcn_readfirstlane(src_sorted[i]);
        const float4 x = *reinterpret_cast<const float4*>(&hs[(size_t)s * 256 + lane * 4]);
        float t0 = x.x + y4.x; t0 = fmaxf(t0, NEG * t0);
        float t1 = x.y + y4.y; t1 = fmaxf(t1, NEG * t1);
        float t2 = x.z + y4.z; t2 = fmaxf(t2, NEG * t2);
        float t3 = x.w + y4.w; t3 = fmaxf(t3, NEG * t3);
        float p = t0 * a4.x;
        p = fmaf(t1, a4.y, p);
        p = fmaf(t2, a4.z, p);
        p = fmaf(t3, a4.w, p);
        p += __shfl_xor(p, 1);
        p += __shfl_xor(p, 2);
        p += __shfl_xor(p, 4);
        p += __shfl_xor(p, 8);           // all 16 lanes of the head hold the score
        if (p > m + 8.0f) {              // rare deferred rescale (T13)
            float rs = __expf(m - p);    // first edge: exp(-inf)=0, clears zeros
            den *= rs;
            acc.x *= rs; acc.y *= rs; acc.z *= rs; acc.w *= rs;
            m = p;
        }
        float wv = __expf(p - m);        // <= e^8; exact after final normalize
        den += wv;
        acc.x = fmaf(wv, x.x, acc.x);
        acc.y = fmaf(wv, x.y, acc.y);
        acc.z = fmaf(wv, x.z, acc.z);
        acc.w = fmaf(wv, x.w, acc.w);
    }

    if (q == 0) { mw[w][hh] = m; denw[w][hh] = den; }
    accs[w][lane] = acc;
    __syncthreads();

    if (w == 0) {
        // per-head global max across waves
        const float m0 = mw[0][hh], m1 = mw[1][hh], m2v = mw[2][hh], m3 = mw[3][hh];
        const float M = fmaxf(fmaxf(m0, m1), fmaxf(m2v, m3));
        float4 o = make_float4(0.f, 0.f, 0.f, 0.f);
        float dtot = 0.0f;
#pragma unroll
        for (int k = 0; k < 4; ++k) {
            const float mk = mw[k][hh];
            const float sc = (mk == -INFINITY) ? 0.0f : __expf(mk - M);
            dtot = fmaf(denw[k][hh], sc, dtot);
            const float4 av = accs[k][lane];
            o.x = fmaf(av.x, sc, o.x);
            o.y = fmaf(av.y, sc, o.y);
            o.z = fmaf(av.z, sc, o.z);
            o.w = fmaf(av.w, sc, o.w);
        }
        const float inv = (dtot > 0.0f) ? 1.0f / dtot : 0.0f;
        o.x *= inv; o.y *= inv; o.z *= inv; o.w *= inv;
        // ELU
        o.x = (o.x > 0.0f) ? o.x : __expf(o.x) - 1.0f;
        o.y = (o.y > 0.0f) ? o.y : __expf(o.y) - 1.0f;
        o.z = (o.z > 0.0f) ? o.z : __expf(o.z) - 1.0f;
        o.w = (o.w > 0.0f) ? o.w : __expf(o.w) - 1.0f;
        // fused layer-2 projection: rows 4*lane..4*lane+3 of W2 [256][2]
        const float4 wsa = *reinterpret_cast<const float4*>(&W2s[lane * 8]);
        const float4 wsb = *reinterpret_cast<const float4*>(&W2s[lane * 8 + 4]);
        const float4 wda = *reinterpret_cast<const float4*>(&W2d[lane * 8]);
        const float4 wdb = *reinterpret_cast<const float4*>(&W2d[lane * 8 + 4]);
        float ps0 = o.x * wsa.x + o.y * wsa.z + o.z * wsb.x + o.w * wsb.z;
        float ps1 = o.x * wsa.y + o.y * wsa.w + o.z * wsb.y + o.w * wsb.w;
        float pd0 = o.x * wda.x + o.y * wda.z + o.z * wdb.x + o.w * wdb.z;
        float pd1 = o.x * wda.y + o.y * wda.w + o.z * wdb.y + o.w * wdb.w;
#pragma unroll
        for (int off = 32; off; off >>= 1) {
            ps0 += __shfl_xor(ps0, off);
            ps1 += __shfl_xor(ps1, off);
            pd0 += __shfl_xor(pd0, off);
            pd1 += __shfl_xor(pd1, off);
        }
        if (lane == 0) {
            hs2[(size_t)n * 2 + 0] = ps0 + b2s[0];
            hs2[(size_t)n * 2 + 1] = ps1 + b2s[1];
            hd2[(size_t)n * 2 + 0] = pd0 + b2d[0];
            hd2[(size_t)n * 2 + 1] = pd1 + b2d[1];
        }
    }
}

// ---------------- Layer-2: wave per node, lane per edge ----------------
__global__ __launch_bounds__(256) void node2_kernel(
    const float* __restrict__ hs2, const float* __restrict__ hd2,
    const float* __restrict__ attn2, const int* __restrict__ src_sorted,
    const int* __restrict__ row_start, float* __restrict__ out)
{
    const int n = blockIdx.x * 4 + (threadIdx.x >> 6);
    const int lane = threadIdx.x & 63;
    if (n >= NN) return;
    const float a0 = attn2[0], a1 = attn2[1];
    const float h0 = hd2[n * 2 + 0], h1v = hd2[n * 2 + 1];
    const int beg = row_start[n], end_ = row_start[n + 1];
    float m = -INFINITY, den = 0.0f, A0 = 0.0f, A1 = 0.0f;
    for (int i = beg + lane; i < end_; i += 64) {
        const int s = src_sorted[i];
        float x0 = hs2[s * 2 + 0], x1 = hs2[s * 2 + 1];
        float t0 = x0 + h0;  t0 = fmaxf(t0, NEG * t0);
        float t1 = x1 + h1v; t1 = fmaxf(t1, NEG * t1);
        float p = fmaf(t0, a0, t1 * a1);
        float mn = fmaxf(m, p);
        float c = __expf(m - mn);
        float w = __expf(p - mn);
        den = den * c + w;
        A0 = A0 * c + w * x0;
        A1 = A1 * c + w * x1;
        m = mn;
    }
#pragma unroll
    for (int off = 1; off < 64; off <<= 1) {
        float m2 = __shfl_xor(m, off);
        float d2 = __shfl_xor(den, off);
        float b0 = __shfl_xor(A0, off);
        float b1 = __shfl_xor(A1, off);
        float mn = fmaxf(m, m2);
        float c1 = (m < mn) ? __expf(m - mn) : 1.0f;
        float c2 = (m2 < mn) ? __expf(m2 - mn) : 1.0f;
        den = den * c1 + d2 * c2;
        A0 = A0 * c1 + b0 * c2;
        A1 = A1 * c1 + b1 * c2;
        m = mn;
    }
    if (lane == 0) {
        out[n * 2 + 0] = (den > 0.0f) ? A0 / den : 0.0f;
        out[n * 2 + 1] = (den > 0.0f) ? A1 / den : 0.0f;
    }
}

// ---------------- launch ----------------
extern "C" void kernel_launch(void* const* d_in, const int* in_sizes, int n_in,
                              void* d_out, int out_size, void* d_ws, size_t ws_size,
                              hipStream_t stream)
{
    const float* feat  = (const float*)d_in[0];
    const int*   src   = (const int*)d_in[1];
    const int*   dst   = (const int*)d_in[2];
    const float* W1s   = (const float*)d_in[3];
    const float* b1s   = (const float*)d_in[4];
    const float* W1d   = (const float*)d_in[5];
    const float* b1d   = (const float*)d_in[6];
    const float* attn1 = (const float*)d_in[7];
    const float* W2s   = (const float*)d_in[8];
    const float* b2s   = (const float*)d_in[9];
    const float* W2d   = (const float*)d_in[10];
    const float* b2d   = (const float*)d_in[11];
    const float* attn2 = (const float*)d_in[12];
    float* out = (float*)d_out;

    char* ws = (char*)d_ws;
    size_t off = 0;
    auto alloc = [&](size_t bytes) {
        char* p = ws + off;
        off += (bytes + 255) & ~size_t(255);
        return p;
    };
    float* hs1        = (float*)alloc((size_t)NN * 256 * 4);
    float* hd1        = (float*)alloc((size_t)NN * 256 * 4);
    int*   src_sorted = (int*)alloc((size_t)NE * 4);
    int*   row_start  = (int*)alloc((size_t)(NN + 1) * 4);
    int*   deg        = (int*)alloc((size_t)NN * 4);
    int*   cursor    = (int*)alloc((size_t)NN * 4);
    int*   bsum       = (int*)alloc((size_t)NB * 4);
    float* hs2        = (float*)alloc((size_t)NN * 2 * 4);
    float* hd2        = (float*)alloc((size_t)NN * 2 * 4);
    (void)ws_size; (void)n_in; (void)in_sizes; (void)out_size;

    hipMemsetAsync(deg, 0, (size_t)NN * 4, stream);
    hipMemsetAsync(cursor, 0, (size_t)NN * 4, stream);

    dim3 ggrid((NN + 63) / 64, 2);
    gemm_proj<<<ggrid, 256, 0, stream>>>(feat, W1s, b1s, hs1, W1d, b1d, hd1, NN);

    const int eb = (NE + 255) / 256;
    count_deg<<<eb, 256, 0, stream>>>(dst, deg);
    deg_blocksum<<<NB, 256, 0, stream>>>(deg, bsum);
    scan_bsum<<<1, 256, 0, stream>>>(bsum);
    write_rows<<<NB, 256, 0, stream>>>(deg, bsum, row_start);
    scatter_src<<<eb, 256, 0, stream>>>(src, dst, row_start, cursor, src_sorted);

    gat1_fused<<<NN, 256, 0, stream>>>(hs1, hd1, attn1, src_sorted, row_start,
                                       W2s, b2s, W2d, b2d, hs2, hd2);

    node2_kernel<<<(NN + 3) / 4, 256, 0, stream>>>(hs2, hd2, attn2, src_sorted,
                                                   row_start, out);
}